// Round 10
// baseline (176.726 us; speedup 1.0000x reference)
//
#include <hip/hip_runtime.h>
#include <hip/hip_bf16.h>

// GCN forward: 2x GCNConv(64->64) + ReLU between, then Linear(64->2).
// N=100000 nodes, E=1250000 edges, F=64.
//
// Round 10: k_part was occupancy-starved (153 blocks, 5.4%). Buckets widen to
// 512 nodes (NBUK=196) so CHUNK can drop to 2048 (611 blocks) at the same
// ~10.5-record run length. Records cached in regs across the two passes.
// k_bfill reworked for 512-node buckets (pair scan). k_gemm gets software
// prefetch of the next X tile + 1024-block grid (6 iters/wave).
//
//  1. gcnt=0; k_part (bucket records); k_bscan; k_bfill (CSR + dinv)
//  2. Hsb = bf16(dinv * (x @ W1))                              k_gemm
//  3. mid = b1 + dinv_i*(Hsb_i + sum Hsb[col])  (fp32)         k_gather<0>
//  4. Hsb = bf16(dinv * (relu(mid) @ W2))                      k_gemm(relu)
//  5. out = (b2 + dinv_i*(Hsb_i + sum Hsb[col])) @ Wlin+blin   k_gather<1>

#define FDIM 64
#define BKT_BITS 9
#define BKT 512               // nodes per bucket
#define CAP 8192              // records per bucket (mean ~6400)
#define CHUNK 2048            // edges per partition block (8 per thread)

__device__ __forceinline__ unsigned short f2b(float f) {
    unsigned u = __float_as_uint(f);
    u += 0x7fff + ((u >> 16) & 1);     // RNE
    return (unsigned short)(u >> 16);
}
__device__ __forceinline__ void unpk(unsigned u, float& lo, float& hi) {
    lo = __uint_as_float(u << 16);
    hi = __uint_as_float(u & 0xffff0000u);
}

__global__ __launch_bounds__(256) void k_zero_g(int* __restrict__ g, int nb) {
    int i = blockIdx.x * blockDim.x + threadIdx.x;
    if (i < nb) g[i] = 0;
}

__global__ __launch_bounds__(256) void k_part(const int* __restrict__ src,
                                              const int* __restrict__ dst,
                                              int* __restrict__ gcnt,
                                              unsigned* __restrict__ rec,
                                              int nE, int nb) {
    __shared__ int lh[256];
    __shared__ int rc[256];
    int t = threadIdx.x;
    if (t < nb) lh[t] = 0;
    __syncthreads();
    int e0 = blockIdx.x * CHUNK;
    int e1 = min(nE, e0 + CHUNK);
    int myb[8];
    unsigned myr[8];
    int cnt = 0;
    for (int i = e0 + t; i < e1; i += 256) {
        int d = dst[i];
        int s = src[i];
        int b = d >> BKT_BITS;
        myb[cnt] = b;
        myr[cnt] = (unsigned)s | ((unsigned)(d & (BKT - 1)) << 17);
        ++cnt;
        atomicAdd(&lh[b], 1);
    }
    __syncthreads();
    if (t < nb) {
        int c = lh[t];
        rc[t] = t * CAP + (c ? atomicAdd(&gcnt[t], c) : 0);
    }
    __syncthreads();
    for (int j = 0; j < cnt; ++j) {
        int b = myb[j];
        int pos = atomicAdd(&rc[b], 1);
        if (pos < (b + 1) * CAP)             // safety clamp (not hit for this input)
            rec[pos] = myr[j];
    }
}

// single block: base = exclusive scan of gcnt[0..nb); base[nb]=nE; rowptr[n]=nE
__global__ __launch_bounds__(256) void k_bscan(const int* __restrict__ gcnt,
                                               int* __restrict__ base,
                                               int* __restrict__ rowptr,
                                               int nb, int nE, int n) {
    int t = threadIdx.x;
    int b0 = t * 4;
    int v[4];
    int run = 0;
#pragma unroll
    for (int j = 0; j < 4; ++j) {
        int idx = b0 + j;
        int c = (idx < nb) ? gcnt[idx] : 0;
        v[j] = run;
        run += c;
    }
    int lane = t & 63, w = t >> 6;
    int inc = run;
#pragma unroll
    for (int off = 1; off < 64; off <<= 1) {
        int x = __shfl_up(inc, off);
        if (lane >= off) inc += x;
    }
    __shared__ int wt[4];
    if (lane == 63) wt[w] = inc;
    __syncthreads();
    int woff = 0;
    for (int i = 0; i < w; ++i) woff += wt[i];
    int gb = woff + (inc - run);
#pragma unroll
    for (int j = 0; j < 4; ++j) {
        int idx = b0 + j;
        if (idx < nb) base[idx] = gb + v[j];
    }
    if (t == 0) { base[nb] = nE; rowptr[n] = nE; }
}

// per bucket (512 nodes): LDS degree count -> pair scan -> rowptr/dinv/cursors
// -> col fill within the bucket's contiguous CSR window
__global__ __launch_bounds__(256) void k_bfill(const unsigned* __restrict__ rec,
                                               const int* __restrict__ gcnt,
                                               const int* __restrict__ base,
                                               int* __restrict__ rowptr,
                                               float* __restrict__ dinv,
                                               int* __restrict__ col, int n) {
    __shared__ int deg[BKT];
    __shared__ int cur[BKT];
    __shared__ int wt[4];
    int b = blockIdx.x, t = threadIdx.x;
    deg[t] = 0;
    deg[t + 256] = 0;
    __syncthreads();
    int rb = b * CAP;
    int re = rb + min(gcnt[b], CAP);
    for (int i = rb + t; i < re; i += 256)
        atomicAdd(&deg[rec[i] >> 17], 1);
    __syncthreads();
    {
        int d0 = deg[2 * t], d1 = deg[2 * t + 1];
        int run = d0 + d1;
        int lane = t & 63, w = t >> 6;
        int inc = run;
#pragma unroll
        for (int off = 1; off < 64; off <<= 1) {
            int x = __shfl_up(inc, off);
            if (lane >= off) inc += x;
        }
        if (lane == 63) wt[w] = inc;
        __syncthreads();
        int woff = 0;
        for (int i = 0; i < w; ++i) woff += wt[i];
        int ex = base[b] + woff + (inc - run);   // exclusive prefix of this pair
        int off0 = ex, off1 = ex + d0;
        int node0 = b * BKT;
        int n0 = node0 + 2 * t, n1 = node0 + 2 * t + 1;
        if (n0 < n) { rowptr[n0] = off0; dinv[n0] = rsqrtf((float)(d0 + 1)); }
        if (n1 < n) { rowptr[n1] = off1; dinv[n1] = rsqrtf((float)(d1 + 1)); }
        cur[2 * t] = off0;
        cur[2 * t + 1] = off1;
    }
    __syncthreads();
    for (int i = rb + t; i < re; i += 256) {
        unsigned u = rec[i];
        int pos = atomicAdd(&cur[u >> 17], 1);
        col[pos] = (int)(u & 0x1FFFF);
    }
}

// Yb[row] = bf16(dinv[row] * (act(X[row]) @ W)); wave = 4 rows, 16 lanes x
// float4; software-prefetch of the next row-tile's X.
__global__ __launch_bounds__(256) void k_gemm(const float* __restrict__ X,
                                              const float* __restrict__ W,
                                              const float* __restrict__ dinv,
                                              unsigned short* __restrict__ Yb,
                                              int n, int relu) {
    __shared__ float Wl[FDIM * FDIM];
    for (int i = threadIdx.x * 4; i < FDIM * FDIM; i += 1024)
        *(float4*)&Wl[i] = *(const float4*)&W[i];
    __syncthreads();
    int t = threadIdx.x, lane = t & 63;
    int g = lane >> 4;              // sub-row 0..3
    int fl = (lane & 15) * 4;       // feature base
    int wave = (blockIdx.x * blockDim.x + t) >> 6;
    int nw = (gridDim.x * blockDim.x) >> 6;
    int stride = nw * 4;
    int gbase = lane & 48;
    int r0 = wave * 4;
    if (r0 >= n) return;
    int rr = min(r0 + g, n - 1);
    float4 xv = *(const float4*)&X[(size_t)rr * FDIM + fl];
    for (; r0 < n; r0 += stride) {
        int row = r0 + g;
        bool ok = row < n;
        int rn = r0 + stride;
        float4 xnext;
        if (rn < n) {
            int rr2 = min(rn + g, n - 1);
            xnext = *(const float4*)&X[(size_t)rr2 * FDIM + fl];
        }
        float4 xa = xv;
        if (relu) {
            xa.x = fmaxf(xa.x, 0.f); xa.y = fmaxf(xa.y, 0.f);
            xa.z = fmaxf(xa.z, 0.f); xa.w = fmaxf(xa.w, 0.f);
        }
        float ax = 0.f, ay = 0.f, az = 0.f, aw = 0.f;
#pragma unroll
        for (int j = 0; j < 16; ++j) {
            int srcl = gbase + j;
            float x0 = __shfl(xa.x, srcl);
            float x1 = __shfl(xa.y, srcl);
            float x2 = __shfl(xa.z, srcl);
            float x3 = __shfl(xa.w, srcl);
            float4 w0 = *(const float4*)&Wl[(4 * j + 0) * FDIM + fl];
            float4 w1 = *(const float4*)&Wl[(4 * j + 1) * FDIM + fl];
            float4 w2 = *(const float4*)&Wl[(4 * j + 2) * FDIM + fl];
            float4 w3 = *(const float4*)&Wl[(4 * j + 3) * FDIM + fl];
            ax = fmaf(x0, w0.x, ax); ay = fmaf(x0, w0.y, ay); az = fmaf(x0, w0.z, az); aw = fmaf(x0, w0.w, aw);
            ax = fmaf(x1, w1.x, ax); ay = fmaf(x1, w1.y, ay); az = fmaf(x1, w1.z, az); aw = fmaf(x1, w1.w, aw);
            ax = fmaf(x2, w2.x, ax); ay = fmaf(x2, w2.y, ay); az = fmaf(x2, w2.z, az); aw = fmaf(x2, w2.w, aw);
            ax = fmaf(x3, w3.x, ax); ay = fmaf(x3, w3.y, ay); az = fmaf(x3, w3.z, az); aw = fmaf(x3, w3.w, aw);
        }
        if (ok) {
            float dd = dinv[row];
            ushort4 ob;
            ob.x = f2b(ax * dd); ob.y = f2b(ay * dd);
            ob.z = f2b(az * dd); ob.w = f2b(aw * dd);
            *(ushort4*)&Yb[(size_t)row * FDIM + fl] = ob;
        }
        xv = xnext;
    }
}

// out = bias + dinv_i*(Hsb_self + sum Hsb[col]); 8-lane row groups, 8 rows/wave,
// explicit 8-deep load batch. HEAD=1 folds the 64->2 head; HEAD=0 writes fp32.
template <int HEAD>
__global__ __launch_bounds__(256) void k_gather(const unsigned short* __restrict__ Hsb,
                                                const float* __restrict__ dinv,
                                                const int* __restrict__ rowptr,
                                                const int* __restrict__ col,
                                                const float* __restrict__ bias,
                                                const float* __restrict__ Wlin,
                                                const float* __restrict__ blin,
                                                float* __restrict__ out, int n) {
    int t = threadIdx.x, lane = t & 63;
    int g = lane >> 3;              // sub-row 0..7
    int fl = (lane & 7) * 8;        // feature base (8 bf16 = 16B per lane)
    int wave = (blockIdx.x * blockDim.x + t) >> 6;
    int nw = (gridDim.x * blockDim.x) >> 6;
    float4 blA = *(const float4*)&bias[fl];
    float4 blB = *(const float4*)&bias[fl + 4];
    float4 q0, q1, q2, q3;
    float bl0 = 0.f, bl1 = 0.f;
    if (HEAD) {
        q0 = *(const float4*)&Wlin[fl * 2];
        q1 = *(const float4*)&Wlin[fl * 2 + 4];
        q2 = *(const float4*)&Wlin[fl * 2 + 8];
        q3 = *(const float4*)&Wlin[fl * 2 + 12];
        bl0 = blin[0]; bl1 = blin[1];
    }
    for (int r0 = wave * 8; r0 < n; r0 += nw * 8) {
        int row = r0 + g;
        bool ok = row < n;
        int rr = ok ? row : (n - 1);
        int beg = rowptr[rr], end = rowptr[rr + 1];
        uint4 sv = *(const uint4*)&Hsb[(size_t)rr * FDIM + fl];
        float a0, a1, a2, a3, a4, a5, a6, a7;
        unpk(sv.x, a0, a1); unpk(sv.y, a2, a3);
        unpk(sv.z, a4, a5); unpk(sv.w, a6, a7);
        for (int k = beg; k < end; k += 8) {
            uint4 h[8];
#pragma unroll
            for (int j = 0; j < 8; ++j) {
                int kk = k + j;
                int s = col[kk < end ? kk : beg];
                h[j] = *(const uint4*)&Hsb[(size_t)s * FDIM + fl];
            }
#pragma unroll
            for (int j = 0; j < 8; ++j) {
                if (k + j < end) {
                    float l0, l1, l2, l3, l4, l5, l6, l7;
                    unpk(h[j].x, l0, l1); unpk(h[j].y, l2, l3);
                    unpk(h[j].z, l4, l5); unpk(h[j].w, l6, l7);
                    a0 += l0; a1 += l1; a2 += l2; a3 += l3;
                    a4 += l4; a5 += l5; a6 += l6; a7 += l7;
                }
            }
        }
        float dd = dinv[rr];
        float v0 = fmaf(dd, a0, blA.x), v1 = fmaf(dd, a1, blA.y);
        float v2 = fmaf(dd, a2, blA.z), v3 = fmaf(dd, a3, blA.w);
        float v4 = fmaf(dd, a4, blB.x), v5 = fmaf(dd, a5, blB.y);
        float v6 = fmaf(dd, a6, blB.z), v7 = fmaf(dd, a7, blB.w);
        if (HEAD == 0) {
            if (ok) {
                float4 oA; oA.x = v0; oA.y = v1; oA.z = v2; oA.w = v3;
                float4 oB; oB.x = v4; oB.y = v5; oB.z = v6; oB.w = v7;
                *(float4*)&out[(size_t)row * FDIM + fl] = oA;
                *(float4*)&out[(size_t)row * FDIM + fl + 4] = oB;
            }
        } else {
            float p0 = v0 * q0.x + v1 * q0.z + v2 * q1.x + v3 * q1.z
                     + v4 * q2.x + v5 * q2.z + v6 * q3.x + v7 * q3.z;
            float p1 = v0 * q0.y + v1 * q0.w + v2 * q1.y + v3 * q1.w
                     + v4 * q2.y + v5 * q2.w + v6 * q3.y + v7 * q3.w;
#pragma unroll
            for (int m = 4; m >= 1; m >>= 1) {
                p0 += __shfl_xor(p0, m);
                p1 += __shfl_xor(p1, m);
            }
            if (ok && (lane & 7) == 0) {
                out[(size_t)row * 2 + 0] = p0 + bl0;
                out[(size_t)row * 2 + 1] = p1 + bl1;
            }
        }
    }
}

extern "C" void kernel_launch(void* const* d_in, const int* in_sizes, int n_in,
                              void* d_out, int out_size, void* d_ws, size_t ws_size,
                              hipStream_t stream) {
    const float* x    = (const float*)d_in[0];
    const int*   ei   = (const int*)d_in[1];   // [2, E] int32
    const float* W1   = (const float*)d_in[3];
    const float* b1   = (const float*)d_in[4];
    const float* W2   = (const float*)d_in[5];
    const float* b2   = (const float*)d_in[6];
    const float* Wlin = (const float*)d_in[7];
    const float* blin = (const float*)d_in[8];
    float* out = (float*)d_out;

    const int n  = in_sizes[0] / FDIM;   // 100000
    const int nE = in_sizes[1] / 2;      // 1250000
    const int* src = ei;
    const int* dst = ei + nE;
    const int NBUK = (n + BKT - 1) / BKT;          // 196

    // workspace layout (4B-elem aligned regions):
    int nPad = ((n + 1024) / 1024) * 1024;         // >= n+1
    int nEPad = ((nE + 1023) / 1024) * 1024;
    int*      gcnt   = (int*)d_ws;                 // [1024]
    int*      base   = gcnt + 1024;                // [1024]
    unsigned* rec    = (unsigned*)(base + 1024);   // [NBUK*CAP] ~6.4 MB
    int*      rowptr = (int*)(rec + (size_t)NBUK * CAP);  // [nPad]
    float*    dinv   = (float*)(rowptr + nPad);    // [nPad]
    int*      col    = (int*)(dinv + nPad);        // [nEPad]
    unsigned short* Hsb = (unsigned short*)(col + nEPad); // [nPad*64] bf16
    float*    mid    = (float*)(Hsb + (size_t)nPad * FDIM); // [n*64] fp32

    const int TB = 256;
    int blkP = (nE + CHUNK - 1) / CHUNK;           // 611

    k_zero_g<<<(NBUK + TB - 1) / TB, TB, 0, stream>>>(gcnt, NBUK);
    k_part<<<blkP, TB, 0, stream>>>(src, dst, gcnt, rec, nE, NBUK);
    k_bscan<<<1, TB, 0, stream>>>(gcnt, base, rowptr, NBUK, nE, n);
    k_bfill<<<NBUK, TB, 0, stream>>>(rec, gcnt, base, rowptr, dinv, col, n);

    k_gemm<<<1024, TB, 0, stream>>>(x, W1, dinv, Hsb, n, 0);
    k_gather<0><<<2048, TB, 0, stream>>>(Hsb, dinv, rowptr, col, b1, nullptr, nullptr, mid, n);

    k_gemm<<<1024, TB, 0, stream>>>(mid, W2, dinv, Hsb, n, 1);
    k_gather<1><<<2048, TB, 0, stream>>>(Hsb, dinv, rowptr, col, b2, Wlin, blin, out, n);

    (void)ws_size; (void)n_in; (void)out_size;
}

// Round 11
// 132.454 us; speedup vs baseline: 1.3342x; 1.3342x over previous
//
#include <hip/hip_runtime.h>
#include <hip/hip_bf16.h>

// GCN forward: 2x GCNConv(64->64) + ReLU between, then Linear(64->2).
// N=100000 nodes, E=1250000 edges, F=64.
//
// Round 11: MFMA GEMM. The shuffle-GEMM was LDS-bound (41.7us each, 64
// ds_read_b128 + 64 bpermute per 4 rows). New k_gemm_mfma holds all of W in
// registers as 8 bf16 B-fragments (4 N-chunks x 2 K-chunks) and does 8x
// v_mfma_f32_16x16x32_bf16 per 16-row tile. Layer-1 converts fp32 x ->bf16
// in-register; layer-2 reads bf16 midb (gather<0> now writes packed bf16,
// halving its write traffic) with ReLU as a packed bit-trick.
// Fragment layouts (m89/m91-verified): A row=lane&15,k=(lane>>4)*8+i;
// B col=lane&15 same k; C/D col=lane&15,row=(lane>>4)*4+reg.
//
//  1. gcnt=0; k_part (bucket records); k_bscan; k_bfill (CSR + dinv)
//  2. Hsb = bf16(dinv * (x @ W1))                              k_gemm_mfma<0>
//  3. midb = bf16(b1 + dinv_i*(Hsb_i + sum Hsb[col]))          k_gather<0>
//  4. Hsb = bf16(dinv * (relu(midb) @ W2))                     k_gemm_mfma<1>
//  5. out = (b2 + dinv_i*(Hsb_i + sum Hsb[col])) @ Wlin+blin   k_gather<1>

#define FDIM 64
#define BKT_BITS 9
#define BKT 512               // nodes per bucket
#define CAP 8192              // records per bucket (mean ~6400)
#define CHUNK 2048            // edges per partition block (8 per thread)

typedef short s16x8 __attribute__((ext_vector_type(8)));
typedef float f32x4 __attribute__((ext_vector_type(4)));

__device__ __forceinline__ unsigned short f2b(float f) {
    unsigned u = __float_as_uint(f);
    u += 0x7fff + ((u >> 16) & 1);     // RNE
    return (unsigned short)(u >> 16);
}
__device__ __forceinline__ void unpk(unsigned u, float& lo, float& hi) {
    lo = __uint_as_float(u << 16);
    hi = __uint_as_float(u & 0xffff0000u);
}
__device__ __forceinline__ unsigned packb(float lo, float hi) {
    return (unsigned)f2b(lo) | ((unsigned)f2b(hi) << 16);
}
// relu on two packed bf16 halves of a 32-bit word
__device__ __forceinline__ unsigned relu2(unsigned u) {
    unsigned t = (u >> 15) & 0x00010001u;
    return u & ~(t * 0xFFFFu);
}

__global__ __launch_bounds__(256) void k_zero_g(int* __restrict__ g, int nb) {
    int i = blockIdx.x * blockDim.x + threadIdx.x;
    if (i < nb) g[i] = 0;
}

__global__ __launch_bounds__(256) void k_part(const int* __restrict__ src,
                                              const int* __restrict__ dst,
                                              int* __restrict__ gcnt,
                                              unsigned* __restrict__ rec,
                                              int nE, int nb) {
    __shared__ int lh[256];
    __shared__ int rc[256];
    int t = threadIdx.x;
    if (t < nb) lh[t] = 0;
    __syncthreads();
    int e0 = blockIdx.x * CHUNK;
    int e1 = min(nE, e0 + CHUNK);
    int myb[8];
    unsigned myr[8];
#pragma unroll
    for (int j = 0; j < 8; ++j) {
        int i = e0 + t + j * 256;
        if (i < e1) {
            int d = dst[i];
            int s = src[i];
            int b = d >> BKT_BITS;
            myb[j] = b;
            myr[j] = (unsigned)s | ((unsigned)(d & (BKT - 1)) << 17);
            atomicAdd(&lh[b], 1);
        } else {
            myb[j] = -1;
        }
    }
    __syncthreads();
    if (t < nb) {
        int c = lh[t];
        rc[t] = t * CAP + (c ? atomicAdd(&gcnt[t], c) : 0);
    }
    __syncthreads();
#pragma unroll
    for (int j = 0; j < 8; ++j) {
        int b = myb[j];
        if (b >= 0) {
            int pos = atomicAdd(&rc[b], 1);
            if (pos < (b + 1) * CAP)         // safety clamp (not hit for this input)
                rec[pos] = myr[j];
        }
    }
}

// single block: base = exclusive scan of gcnt[0..nb); base[nb]=nE; rowptr[n]=nE
__global__ __launch_bounds__(256) void k_bscan(const int* __restrict__ gcnt,
                                               int* __restrict__ base,
                                               int* __restrict__ rowptr,
                                               int nb, int nE, int n) {
    int t = threadIdx.x;
    int b0 = t * 4;
    int v[4];
    int run = 0;
#pragma unroll
    for (int j = 0; j < 4; ++j) {
        int idx = b0 + j;
        int c = (idx < nb) ? gcnt[idx] : 0;
        v[j] = run;
        run += c;
    }
    int lane = t & 63, w = t >> 6;
    int inc = run;
#pragma unroll
    for (int off = 1; off < 64; off <<= 1) {
        int x = __shfl_up(inc, off);
        if (lane >= off) inc += x;
    }
    __shared__ int wt[4];
    if (lane == 63) wt[w] = inc;
    __syncthreads();
    int woff = 0;
    for (int i = 0; i < w; ++i) woff += wt[i];
    int gb = woff + (inc - run);
#pragma unroll
    for (int j = 0; j < 4; ++j) {
        int idx = b0 + j;
        if (idx < nb) base[idx] = gb + v[j];
    }
    if (t == 0) { base[nb] = nE; rowptr[n] = nE; }
}

// per bucket (512 nodes): LDS degree count -> pair scan -> rowptr/dinv/cursors
// -> col fill within the bucket's contiguous CSR window
__global__ __launch_bounds__(256) void k_bfill(const unsigned* __restrict__ rec,
                                               const int* __restrict__ gcnt,
                                               const int* __restrict__ base,
                                               int* __restrict__ rowptr,
                                               float* __restrict__ dinv,
                                               int* __restrict__ col, int n) {
    __shared__ int deg[BKT];
    __shared__ int cur[BKT];
    __shared__ int wt[4];
    int b = blockIdx.x, t = threadIdx.x;
    deg[t] = 0;
    deg[t + 256] = 0;
    __syncthreads();
    int rb = b * CAP;
    int re = rb + min(gcnt[b], CAP);
    for (int i = rb + t; i < re; i += 256)
        atomicAdd(&deg[rec[i] >> 17], 1);
    __syncthreads();
    {
        int d0 = deg[2 * t], d1 = deg[2 * t + 1];
        int run = d0 + d1;
        int lane = t & 63, w = t >> 6;
        int inc = run;
#pragma unroll
        for (int off = 1; off < 64; off <<= 1) {
            int x = __shfl_up(inc, off);
            if (lane >= off) inc += x;
        }
        if (lane == 63) wt[w] = inc;
        __syncthreads();
        int woff = 0;
        for (int i = 0; i < w; ++i) woff += wt[i];
        int ex = base[b] + woff + (inc - run);
        int off0 = ex, off1 = ex + d0;
        int node0 = b * BKT;
        int n0 = node0 + 2 * t, n1 = node0 + 2 * t + 1;
        if (n0 < n) { rowptr[n0] = off0; dinv[n0] = rsqrtf((float)(d0 + 1)); }
        if (n1 < n) { rowptr[n1] = off1; dinv[n1] = rsqrtf((float)(d1 + 1)); }
        cur[2 * t] = off0;
        cur[2 * t + 1] = off1;
    }
    __syncthreads();
    for (int i = rb + t; i < re; i += 256) {
        unsigned u = rec[i];
        int pos = atomicAdd(&cur[u >> 17], 1);
        col[pos] = (int)(u & 0x1FFFF);
    }
}

// MFMA GEMM: Yb[r] = bf16(dinv[r] * (act(X[r]) @ W)), X is [n,64], W [64,64].
// One wave computes a 16-row x 64-col tile: 8x mfma_f32_16x16x32_bf16.
// INBF=0: X fp32 (no act). INBF=1: X bf16 + ReLU (packed bit-trick).
template <int INBF>
__global__ __launch_bounds__(256) void k_gemm_mfma(const void* __restrict__ Xv,
                                                   const float* __restrict__ W,
                                                   const float* __restrict__ dinv,
                                                   unsigned short* __restrict__ Yb,
                                                   int n) {
    int t = threadIdx.x, lane = t & 63;
    int ln = lane & 15;          // N index within chunk / A row
    int kq = lane >> 4;          // K quarter (8 elems each)
    int wave = (blockIdx.x * blockDim.x + t) >> 6;
    int nw = (gridDim.x * blockDim.x) >> 6;

    // B fragments: bf[nc][kc], lane holds W[kc*32+kq*8+i][nc*16+ln], i=0..7
    s16x8 bf[4][2];
#pragma unroll
    for (int nc = 0; nc < 4; ++nc) {
#pragma unroll
        for (int kc = 0; kc < 2; ++kc) {
            s16x8 s;
#pragma unroll
            for (int i = 0; i < 8; ++i) {
                int k = kc * 32 + kq * 8 + i;
                s[i] = (short)f2b(W[k * FDIM + nc * 16 + ln]);
            }
            bf[nc][kc] = s;
        }
    }

    int ntile = (n + 15) >> 4;
    for (int tile = wave; tile < ntile; tile += nw) {
        int rowbase = tile << 4;
        int arow = rowbase + ln;
        if (arow >= n) arow = n - 1;
        s16x8 a0, a1;
        if (INBF) {
            const unsigned short* Xb = (const unsigned short*)Xv;
            uint4 u0 = *(const uint4*)&Xb[(size_t)arow * FDIM + kq * 8];
            uint4 u1 = *(const uint4*)&Xb[(size_t)arow * FDIM + 32 + kq * 8];
            u0.x = relu2(u0.x); u0.y = relu2(u0.y); u0.z = relu2(u0.z); u0.w = relu2(u0.w);
            u1.x = relu2(u1.x); u1.y = relu2(u1.y); u1.z = relu2(u1.z); u1.w = relu2(u1.w);
            a0 = *reinterpret_cast<const s16x8*>(&u0);
            a1 = *reinterpret_cast<const s16x8*>(&u1);
        } else {
            const float* Xf = (const float*)Xv;
            const float* p = Xf + (size_t)arow * FDIM + kq * 8;
            float4 f0 = *(const float4*)p;
            float4 f1 = *(const float4*)(p + 4);
            float4 f2 = *(const float4*)(p + 32);
            float4 f3 = *(const float4*)(p + 36);
            a0[0] = (short)f2b(f0.x); a0[1] = (short)f2b(f0.y);
            a0[2] = (short)f2b(f0.z); a0[3] = (short)f2b(f0.w);
            a0[4] = (short)f2b(f1.x); a0[5] = (short)f2b(f1.y);
            a0[6] = (short)f2b(f1.z); a0[7] = (short)f2b(f1.w);
            a1[0] = (short)f2b(f2.x); a1[1] = (short)f2b(f2.y);
            a1[2] = (short)f2b(f2.z); a1[3] = (short)f2b(f2.w);
            a1[4] = (short)f2b(f3.x); a1[5] = (short)f2b(f3.y);
            a1[6] = (short)f2b(f3.z); a1[7] = (short)f2b(f3.w);
        }
        f32x4 acc[4];
#pragma unroll
        for (int nc = 0; nc < 4; ++nc) {
            f32x4 z = {0.f, 0.f, 0.f, 0.f};
            acc[nc] = __builtin_amdgcn_mfma_f32_16x16x32_bf16(a0, bf[nc][0], z, 0, 0, 0);
            acc[nc] = __builtin_amdgcn_mfma_f32_16x16x32_bf16(a1, bf[nc][1], acc[nc], 0, 0, 0);
        }
        // C/D: col = nc*16+ln, row(tile) = kq*4+reg
        int r0 = rowbase + kq * 4;
        float dd[4];
#pragma unroll
        for (int j = 0; j < 4; ++j) {
            int r = r0 + j;
            dd[j] = dinv[r < n ? r : (n - 1)];
        }
#pragma unroll
        for (int nc = 0; nc < 4; ++nc) {
#pragma unroll
            for (int j = 0; j < 4; ++j) {
                int r = r0 + j;
                if (r < n)
                    Yb[(size_t)r * FDIM + nc * 16 + ln] = f2b(acc[nc][j] * dd[j]);
            }
        }
    }
}

// out = bias + dinv_i*(Hsb_self + sum Hsb[col]); 8-lane row groups, 8 rows/wave,
// explicit 8-deep load batch. HEAD=0 writes packed bf16 [n,64]; HEAD=1 folds
// the 64->2 head and writes fp32 [n,2].
template <int HEAD>
__global__ __launch_bounds__(256) void k_gather(const unsigned short* __restrict__ Hsb,
                                                const float* __restrict__ dinv,
                                                const int* __restrict__ rowptr,
                                                const int* __restrict__ col,
                                                const float* __restrict__ bias,
                                                const float* __restrict__ Wlin,
                                                const float* __restrict__ blin,
                                                void* __restrict__ outp, int n) {
    int t = threadIdx.x, lane = t & 63;
    int g = lane >> 3;              // sub-row 0..7
    int fl = (lane & 7) * 8;        // feature base (8 bf16 = 16B per lane)
    int wave = (blockIdx.x * blockDim.x + t) >> 6;
    int nw = (gridDim.x * blockDim.x) >> 6;
    float4 blA = *(const float4*)&bias[fl];
    float4 blB = *(const float4*)&bias[fl + 4];
    float4 q0, q1, q2, q3;
    float bl0 = 0.f, bl1 = 0.f;
    if (HEAD) {
        q0 = *(const float4*)&Wlin[fl * 2];
        q1 = *(const float4*)&Wlin[fl * 2 + 4];
        q2 = *(const float4*)&Wlin[fl * 2 + 8];
        q3 = *(const float4*)&Wlin[fl * 2 + 12];
        bl0 = blin[0]; bl1 = blin[1];
    }
    for (int r0 = wave * 8; r0 < n; r0 += nw * 8) {
        int row = r0 + g;
        bool ok = row < n;
        int rr = ok ? row : (n - 1);
        int beg = rowptr[rr], end = rowptr[rr + 1];
        uint4 sv = *(const uint4*)&Hsb[(size_t)rr * FDIM + fl];
        float a0, a1, a2, a3, a4, a5, a6, a7;
        unpk(sv.x, a0, a1); unpk(sv.y, a2, a3);
        unpk(sv.z, a4, a5); unpk(sv.w, a6, a7);
        for (int k = beg; k < end; k += 8) {
            uint4 h[8];
#pragma unroll
            for (int j = 0; j < 8; ++j) {
                int kk = k + j;
                int s = col[kk < end ? kk : beg];
                h[j] = *(const uint4*)&Hsb[(size_t)s * FDIM + fl];
            }
#pragma unroll
            for (int j = 0; j < 8; ++j) {
                if (k + j < end) {
                    float l0, l1, l2, l3, l4, l5, l6, l7;
                    unpk(h[j].x, l0, l1); unpk(h[j].y, l2, l3);
                    unpk(h[j].z, l4, l5); unpk(h[j].w, l6, l7);
                    a0 += l0; a1 += l1; a2 += l2; a3 += l3;
                    a4 += l4; a5 += l5; a6 += l6; a7 += l7;
                }
            }
        }
        float dd = dinv[rr];
        float v0 = fmaf(dd, a0, blA.x), v1 = fmaf(dd, a1, blA.y);
        float v2 = fmaf(dd, a2, blA.z), v3 = fmaf(dd, a3, blA.w);
        float v4 = fmaf(dd, a4, blB.x), v5 = fmaf(dd, a5, blB.y);
        float v6 = fmaf(dd, a6, blB.z), v7 = fmaf(dd, a7, blB.w);
        if (HEAD == 0) {
            if (ok) {
                unsigned short* ob = (unsigned short*)outp;
                uint4 o;
                o.x = packb(v0, v1); o.y = packb(v2, v3);
                o.z = packb(v4, v5); o.w = packb(v6, v7);
                *(uint4*)&ob[(size_t)row * FDIM + fl] = o;
            }
        } else {
            float p0 = v0 * q0.x + v1 * q0.z + v2 * q1.x + v3 * q1.z
                     + v4 * q2.x + v5 * q2.z + v6 * q3.x + v7 * q3.z;
            float p1 = v0 * q0.y + v1 * q0.w + v2 * q1.y + v3 * q1.w
                     + v4 * q2.y + v5 * q2.w + v6 * q3.y + v7 * q3.w;
#pragma unroll
            for (int m = 4; m >= 1; m >>= 1) {
                p0 += __shfl_xor(p0, m);
                p1 += __shfl_xor(p1, m);
            }
            if (ok && (lane & 7) == 0) {
                float* of = (float*)outp;
                of[(size_t)row * 2 + 0] = p0 + bl0;
                of[(size_t)row * 2 + 1] = p1 + bl1;
            }
        }
    }
}

extern "C" void kernel_launch(void* const* d_in, const int* in_sizes, int n_in,
                              void* d_out, int out_size, void* d_ws, size_t ws_size,
                              hipStream_t stream) {
    const float* x    = (const float*)d_in[0];
    const int*   ei   = (const int*)d_in[1];   // [2, E] int32
    const float* W1   = (const float*)d_in[3];
    const float* b1   = (const float*)d_in[4];
    const float* W2   = (const float*)d_in[5];
    const float* b2   = (const float*)d_in[6];
    const float* Wlin = (const float*)d_in[7];
    const float* blin = (const float*)d_in[8];
    float* out = (float*)d_out;

    const int n  = in_sizes[0] / FDIM;   // 100000
    const int nE = in_sizes[1] / 2;      // 1250000
    const int* src = ei;
    const int* dst = ei + nE;
    const int NBUK = (n + BKT - 1) / BKT;          // 196

    // workspace layout (4B-elem aligned regions):
    int nPad = ((n + 1024) / 1024) * 1024;         // >= n+1
    int nEPad = ((nE + 1023) / 1024) * 1024;
    int*      gcnt   = (int*)d_ws;                 // [1024]
    int*      base   = gcnt + 1024;                // [1024]
    unsigned* rec    = (unsigned*)(base + 1024);   // [NBUK*CAP] ~6.4 MB
    int*      rowptr = (int*)(rec + (size_t)NBUK * CAP);  // [nPad]
    float*    dinv   = (float*)(rowptr + nPad);    // [nPad]
    int*      col    = (int*)(dinv + nPad);        // [nEPad]
    unsigned short* Hsb  = (unsigned short*)(col + nEPad);        // [nPad*64] bf16
    unsigned short* midb = Hsb + (size_t)nPad * FDIM;             // [nPad*64] bf16

    const int TB = 256;
    int blkP = (nE + CHUNK - 1) / CHUNK;           // 611

    k_zero_g<<<(NBUK + TB - 1) / TB, TB, 0, stream>>>(gcnt, NBUK);
    k_part<<<blkP, TB, 0, stream>>>(src, dst, gcnt, rec, nE, NBUK);
    k_bscan<<<1, TB, 0, stream>>>(gcnt, base, rowptr, NBUK, nE, n);
    k_bfill<<<NBUK, TB, 0, stream>>>(rec, gcnt, base, rowptr, dinv, col, n);

    k_gemm_mfma<0><<<512, TB, 0, stream>>>(x, W1, dinv, Hsb, n);
    k_gather<0><<<2048, TB, 0, stream>>>(Hsb, dinv, rowptr, col, b1, nullptr, nullptr, midb, n);

    k_gemm_mfma<1><<<512, TB, 0, stream>>>(midb, W2, dinv, Hsb, n);
    k_gather<1><<<2048, TB, 0, stream>>>(Hsb, dinv, rowptr, col, b2, Wlin, blin, out, n);

    (void)ws_size; (void)n_in; (void)out_size;
}

// Round 12
// 132.215 us; speedup vs baseline: 1.3367x; 1.0018x over previous
//
#include <hip/hip_runtime.h>
#include <hip/hip_bf16.h>

// GCN forward: 2x GCNConv(64->64) + ReLU between, then Linear(64->2).
// N=100000 nodes, E=1250000 edges, F=64.
//
// Round 12: overhead trim. (1) k_bscan deleted — each k_bfill block computes
// its own bucket base by summing gcnt[0..b) (wave-0 reduce). (2) BKT 512->256
// (391 blocks) to double k_bfill occupancy. (3) gathers double-buffer the col
// batch (preload next 8 indices while current 8 row-loads are in flight).
//
//  1. gcnt=0; k_part (bucket records); k_bfill (prefix + CSR + dinv)
//  2. Hsb = bf16(dinv * (x @ W1))                              k_gemm_mfma<0>
//  3. midb = bf16(b1 + dinv_i*(Hsb_i + sum Hsb[col]))          k_gather<0>
//  4. Hsb = bf16(dinv * (relu(midb) @ W2))                     k_gemm_mfma<1>
//  5. out = (b2 + dinv_i*(Hsb_i + sum Hsb[col])) @ Wlin+blin   k_gather<1>

#define FDIM 64
#define BKT_BITS 8
#define BKT 256               // nodes per bucket
#define CAP 4096              // records per bucket (mean ~3200)
#define CHUNK 2048            // edges per partition block (8 per thread)

typedef short s16x8 __attribute__((ext_vector_type(8)));
typedef float f32x4 __attribute__((ext_vector_type(4)));

__device__ __forceinline__ unsigned short f2b(float f) {
    unsigned u = __float_as_uint(f);
    u += 0x7fff + ((u >> 16) & 1);     // RNE
    return (unsigned short)(u >> 16);
}
__device__ __forceinline__ void unpk(unsigned u, float& lo, float& hi) {
    lo = __uint_as_float(u << 16);
    hi = __uint_as_float(u & 0xffff0000u);
}
__device__ __forceinline__ unsigned packb(float lo, float hi) {
    return (unsigned)f2b(lo) | ((unsigned)f2b(hi) << 16);
}
// relu on two packed bf16 halves of a 32-bit word
__device__ __forceinline__ unsigned relu2(unsigned u) {
    unsigned t = (u >> 15) & 0x00010001u;
    return u & ~(t * 0xFFFFu);
}

__global__ __launch_bounds__(256) void k_zero_g(int* __restrict__ g, int nb) {
    int i = blockIdx.x * blockDim.x + threadIdx.x;
    if (i < nb) g[i] = 0;
}

__global__ __launch_bounds__(256) void k_part(const int* __restrict__ src,
                                              const int* __restrict__ dst,
                                              int* __restrict__ gcnt,
                                              unsigned* __restrict__ rec,
                                              int nE, int nb) {
    __shared__ int lh[512];
    __shared__ int rc[512];
    int t = threadIdx.x;
    for (int b = t; b < nb; b += 256) lh[b] = 0;
    __syncthreads();
    int e0 = blockIdx.x * CHUNK;
    int e1 = min(nE, e0 + CHUNK);
    int myb[8];
    unsigned myr[8];
#pragma unroll
    for (int j = 0; j < 8; ++j) {
        int i = e0 + t + j * 256;
        if (i < e1) {
            int d = dst[i];
            int s = src[i];
            int b = d >> BKT_BITS;
            myb[j] = b;
            myr[j] = (unsigned)s | ((unsigned)(d & (BKT - 1)) << 17);
            atomicAdd(&lh[b], 1);
        } else {
            myb[j] = -1;
        }
    }
    __syncthreads();
    for (int b = t; b < nb; b += 256) {
        int c = lh[b];
        rc[b] = b * CAP + (c ? atomicAdd(&gcnt[b], c) : 0);
    }
    __syncthreads();
#pragma unroll
    for (int j = 0; j < 8; ++j) {
        int b = myb[j];
        if (b >= 0) {
            int pos = atomicAdd(&rc[b], 1);
            if (pos < (b + 1) * CAP)         // safety clamp (not hit for this input)
                rec[pos] = myr[j];
        }
    }
}

// per bucket (256 nodes): base = sum gcnt[0..b) (wave-0) -> LDS degree count
// -> scan -> rowptr/dinv/cursors -> col fill within the bucket's CSR window
__global__ __launch_bounds__(256) void k_bfill(const unsigned* __restrict__ rec,
                                               const int* __restrict__ gcnt,
                                               int* __restrict__ rowptr,
                                               float* __restrict__ dinv,
                                               int* __restrict__ col,
                                               int n, int nb, int nE) {
    __shared__ int deg[BKT];
    __shared__ int cur[BKT];
    __shared__ int wt[4];
    __shared__ int sbase;
    int b = blockIdx.x, t = threadIdx.x;
    if (t < 64) {                      // base[b] = exclusive prefix of gcnt
        int s = 0;
        for (int i = t; i < b; i += 64) s += gcnt[i];
#pragma unroll
        for (int off = 32; off >= 1; off >>= 1) s += __shfl_xor(s, off);
        if (t == 0) sbase = s;
    }
    deg[t] = 0;
    if (b == nb - 1 && t == 0) rowptr[n] = nE;
    __syncthreads();
    int rb = b * CAP;
    int re = rb + min(gcnt[b], CAP);
    for (int i = rb + t; i < re; i += 256)
        atomicAdd(&deg[rec[i] >> 17], 1);
    __syncthreads();
    {
        int d0 = deg[t];
        int lane = t & 63, w = t >> 6;
        int inc = d0;
#pragma unroll
        for (int off = 1; off < 64; off <<= 1) {
            int x = __shfl_up(inc, off);
            if (lane >= off) inc += x;
        }
        if (lane == 63) wt[w] = inc;
        __syncthreads();
        int woff = 0;
        for (int i = 0; i < w; ++i) woff += wt[i];
        int ex = sbase + woff + (inc - d0);     // exclusive prefix
        int node = b * BKT + t;
        if (node < n) { rowptr[node] = ex; dinv[node] = rsqrtf((float)(d0 + 1)); }
        cur[t] = ex;
    }
    __syncthreads();
    for (int i = rb + t; i < re; i += 256) {
        unsigned u = rec[i];
        int pos = atomicAdd(&cur[u >> 17], 1);
        col[pos] = (int)(u & 0x1FFFF);
    }
}

// MFMA GEMM: Yb[r] = bf16(dinv[r] * (act(X[r]) @ W)), X is [n,64], W [64,64].
// One wave computes a 16-row x 64-col tile: 8x mfma_f32_16x16x32_bf16.
// INBF=0: X fp32 (no act). INBF=1: X bf16 + ReLU (packed bit-trick).
template <int INBF>
__global__ __launch_bounds__(256) void k_gemm_mfma(const void* __restrict__ Xv,
                                                   const float* __restrict__ W,
                                                   const float* __restrict__ dinv,
                                                   unsigned short* __restrict__ Yb,
                                                   int n) {
    int t = threadIdx.x, lane = t & 63;
    int ln = lane & 15;          // N index within chunk / A row
    int kq = lane >> 4;          // K quarter (8 elems each)
    int wave = (blockIdx.x * blockDim.x + t) >> 6;
    int nw = (gridDim.x * blockDim.x) >> 6;

    // B fragments: bf[nc][kc], lane holds W[kc*32+kq*8+i][nc*16+ln], i=0..7
    s16x8 bf[4][2];
#pragma unroll
    for (int nc = 0; nc < 4; ++nc) {
#pragma unroll
        for (int kc = 0; kc < 2; ++kc) {
            s16x8 s;
#pragma unroll
            for (int i = 0; i < 8; ++i) {
                int k = kc * 32 + kq * 8 + i;
                s[i] = (short)f2b(W[k * FDIM + nc * 16 + ln]);
            }
            bf[nc][kc] = s;
        }
    }

    int ntile = (n + 15) >> 4;
    for (int tile = wave; tile < ntile; tile += nw) {
        int rowbase = tile << 4;
        int arow = rowbase + ln;
        if (arow >= n) arow = n - 1;
        s16x8 a0, a1;
        if (INBF) {
            const unsigned short* Xb = (const unsigned short*)Xv;
            uint4 u0 = *(const uint4*)&Xb[(size_t)arow * FDIM + kq * 8];
            uint4 u1 = *(const uint4*)&Xb[(size_t)arow * FDIM + 32 + kq * 8];
            u0.x = relu2(u0.x); u0.y = relu2(u0.y); u0.z = relu2(u0.z); u0.w = relu2(u0.w);
            u1.x = relu2(u1.x); u1.y = relu2(u1.y); u1.z = relu2(u1.z); u1.w = relu2(u1.w);
            a0 = *reinterpret_cast<const s16x8*>(&u0);
            a1 = *reinterpret_cast<const s16x8*>(&u1);
        } else {
            const float* Xf = (const float*)Xv;
            const float* p = Xf + (size_t)arow * FDIM + kq * 8;
            float4 f0 = *(const float4*)p;
            float4 f1 = *(const float4*)(p + 4);
            float4 f2 = *(const float4*)(p + 32);
            float4 f3 = *(const float4*)(p + 36);
            a0[0] = (short)f2b(f0.x); a0[1] = (short)f2b(f0.y);
            a0[2] = (short)f2b(f0.z); a0[3] = (short)f2b(f0.w);
            a0[4] = (short)f2b(f1.x); a0[5] = (short)f2b(f1.y);
            a0[6] = (short)f2b(f1.z); a0[7] = (short)f2b(f1.w);
            a1[0] = (short)f2b(f2.x); a1[1] = (short)f2b(f2.y);
            a1[2] = (short)f2b(f2.z); a1[3] = (short)f2b(f2.w);
            a1[4] = (short)f2b(f3.x); a1[5] = (short)f2b(f3.y);
            a1[6] = (short)f2b(f3.z); a1[7] = (short)f2b(f3.w);
        }
        f32x4 acc[4];
#pragma unroll
        for (int nc = 0; nc < 4; ++nc) {
            f32x4 z = {0.f, 0.f, 0.f, 0.f};
            acc[nc] = __builtin_amdgcn_mfma_f32_16x16x32_bf16(a0, bf[nc][0], z, 0, 0, 0);
            acc[nc] = __builtin_amdgcn_mfma_f32_16x16x32_bf16(a1, bf[nc][1], acc[nc], 0, 0, 0);
        }
        // C/D: col = nc*16+ln, row(tile) = kq*4+reg
        int r0 = rowbase + kq * 4;
        float dd[4];
#pragma unroll
        for (int j = 0; j < 4; ++j) {
            int r = r0 + j;
            dd[j] = dinv[r < n ? r : (n - 1)];
        }
#pragma unroll
        for (int nc = 0; nc < 4; ++nc) {
#pragma unroll
            for (int j = 0; j < 4; ++j) {
                int r = r0 + j;
                if (r < n)
                    Yb[(size_t)r * FDIM + nc * 16 + ln] = f2b(acc[nc][j] * dd[j]);
            }
        }
    }
}

// out = bias + dinv_i*(Hsb_self + sum Hsb[col]); 8-lane row groups, 8 rows/wave,
// explicit 8-deep load batch with double-buffered col indices.
// HEAD=0 writes packed bf16 [n,64]; HEAD=1 folds the 64->2 head, writes fp32.
template <int HEAD>
__global__ __launch_bounds__(256) void k_gather(const unsigned short* __restrict__ Hsb,
                                                const float* __restrict__ dinv,
                                                const int* __restrict__ rowptr,
                                                const int* __restrict__ col,
                                                const float* __restrict__ bias,
                                                const float* __restrict__ Wlin,
                                                const float* __restrict__ blin,
                                                void* __restrict__ outp, int n) {
    int t = threadIdx.x, lane = t & 63;
    int g = lane >> 3;              // sub-row 0..7
    int fl = (lane & 7) * 8;        // feature base (8 bf16 = 16B per lane)
    int wave = (blockIdx.x * blockDim.x + t) >> 6;
    int nw = (gridDim.x * blockDim.x) >> 6;
    float4 blA = *(const float4*)&bias[fl];
    float4 blB = *(const float4*)&bias[fl + 4];
    float4 q0, q1, q2, q3;
    float bl0 = 0.f, bl1 = 0.f;
    if (HEAD) {
        q0 = *(const float4*)&Wlin[fl * 2];
        q1 = *(const float4*)&Wlin[fl * 2 + 4];
        q2 = *(const float4*)&Wlin[fl * 2 + 8];
        q3 = *(const float4*)&Wlin[fl * 2 + 12];
        bl0 = blin[0]; bl1 = blin[1];
    }
    for (int r0 = wave * 8; r0 < n; r0 += nw * 8) {
        int row = r0 + g;
        bool ok = row < n;
        int rr = ok ? row : (n - 1);
        int beg = rowptr[rr], end = rowptr[rr + 1];
        uint4 sv = *(const uint4*)&Hsb[(size_t)rr * FDIM + fl];
        float a0, a1, a2, a3, a4, a5, a6, a7;
        unpk(sv.x, a0, a1); unpk(sv.y, a2, a3);
        unpk(sv.z, a4, a5); unpk(sv.w, a6, a7);
        int c0[8];
#pragma unroll
        for (int j = 0; j < 8; ++j) c0[j] = 0;
        if (beg < end) {
#pragma unroll
            for (int j = 0; j < 8; ++j) {
                int kk = beg + j;
                c0[j] = col[kk < end ? kk : beg];
            }
        }
        for (int k = beg; k < end; k += 8) {
            int kn = k + 8;
            int c1[8];
#pragma unroll
            for (int j = 0; j < 8; ++j) {
                int kk = kn + j;
                c1[j] = (kn < end) ? col[kk < end ? kk : kn] : 0;
            }
            uint4 h[8];
#pragma unroll
            for (int j = 0; j < 8; ++j)
                h[j] = *(const uint4*)&Hsb[(size_t)c0[j] * FDIM + fl];
#pragma unroll
            for (int j = 0; j < 8; ++j) {
                if (k + j < end) {
                    float l0, l1, l2, l3, l4, l5, l6, l7;
                    unpk(h[j].x, l0, l1); unpk(h[j].y, l2, l3);
                    unpk(h[j].z, l4, l5); unpk(h[j].w, l6, l7);
                    a0 += l0; a1 += l1; a2 += l2; a3 += l3;
                    a4 += l4; a5 += l5; a6 += l6; a7 += l7;
                }
            }
#pragma unroll
            for (int j = 0; j < 8; ++j) c0[j] = c1[j];
        }
        float dd = dinv[rr];
        float v0 = fmaf(dd, a0, blA.x), v1 = fmaf(dd, a1, blA.y);
        float v2 = fmaf(dd, a2, blA.z), v3 = fmaf(dd, a3, blA.w);
        float v4 = fmaf(dd, a4, blB.x), v5 = fmaf(dd, a5, blB.y);
        float v6 = fmaf(dd, a6, blB.z), v7 = fmaf(dd, a7, blB.w);
        if (HEAD == 0) {
            if (ok) {
                unsigned short* ob = (unsigned short*)outp;
                uint4 o;
                o.x = packb(v0, v1); o.y = packb(v2, v3);
                o.z = packb(v4, v5); o.w = packb(v6, v7);
                *(uint4*)&ob[(size_t)row * FDIM + fl] = o;
            }
        } else {
            float p0 = v0 * q0.x + v1 * q0.z + v2 * q1.x + v3 * q1.z
                     + v4 * q2.x + v5 * q2.z + v6 * q3.x + v7 * q3.z;
            float p1 = v0 * q0.y + v1 * q0.w + v2 * q1.y + v3 * q1.w
                     + v4 * q2.y + v5 * q2.w + v6 * q3.y + v7 * q3.w;
#pragma unroll
            for (int m = 4; m >= 1; m >>= 1) {
                p0 += __shfl_xor(p0, m);
                p1 += __shfl_xor(p1, m);
            }
            if (ok && (lane & 7) == 0) {
                float* of = (float*)outp;
                of[(size_t)row * 2 + 0] = p0 + bl0;
                of[(size_t)row * 2 + 1] = p1 + bl1;
            }
        }
    }
}

extern "C" void kernel_launch(void* const* d_in, const int* in_sizes, int n_in,
                              void* d_out, int out_size, void* d_ws, size_t ws_size,
                              hipStream_t stream) {
    const float* x    = (const float*)d_in[0];
    const int*   ei   = (const int*)d_in[1];   // [2, E] int32
    const float* W1   = (const float*)d_in[3];
    const float* b1   = (const float*)d_in[4];
    const float* W2   = (const float*)d_in[5];
    const float* b2   = (const float*)d_in[6];
    const float* Wlin = (const float*)d_in[7];
    const float* blin = (const float*)d_in[8];
    float* out = (float*)d_out;

    const int n  = in_sizes[0] / FDIM;   // 100000
    const int nE = in_sizes[1] / 2;      // 1250000
    const int* src = ei;
    const int* dst = ei + nE;
    const int NBUK = (n + BKT - 1) / BKT;          // 391

    // workspace layout (4B-elem aligned regions):
    int nPad = ((n + 1024) / 1024) * 1024;         // >= n+1
    int nEPad = ((nE + 1023) / 1024) * 1024;
    int*      gcnt   = (int*)d_ws;                 // [1024]
    unsigned* rec    = (unsigned*)(gcnt + 1024);   // [NBUK*CAP] ~6.4 MB
    int*      rowptr = (int*)(rec + (size_t)NBUK * CAP);  // [nPad]
    float*    dinv   = (float*)(rowptr + nPad);    // [nPad]
    int*      col    = (int*)(dinv + nPad);        // [nEPad]
    unsigned short* Hsb  = (unsigned short*)(col + nEPad);        // [nPad*64] bf16
    unsigned short* midb = Hsb + (size_t)nPad * FDIM;             // [nPad*64] bf16

    const int TB = 256;
    int blkP = (nE + CHUNK - 1) / CHUNK;           // 611

    k_zero_g<<<(NBUK + TB - 1) / TB, TB, 0, stream>>>(gcnt, NBUK);
    k_part<<<blkP, TB, 0, stream>>>(src, dst, gcnt, rec, nE, NBUK);
    k_bfill<<<NBUK, TB, 0, stream>>>(rec, gcnt, rowptr, dinv, col, n, NBUK, nE);

    k_gemm_mfma<0><<<512, TB, 0, stream>>>(x, W1, dinv, Hsb, n);
    k_gather<0><<<2048, TB, 0, stream>>>(Hsb, dinv, rowptr, col, b1, nullptr, nullptr, midb, n);

    k_gemm_mfma<1><<<512, TB, 0, stream>>>(midb, W2, dinv, Hsb, n);
    k_gather<1><<<2048, TB, 0, stream>>>(Hsb, dinv, rowptr, col, b2, Wlin, blin, out, n);

    (void)ws_size; (void)n_in; (void)out_size;
}